// Round 3
// baseline (137.170 us; speedup 1.0000x reference)
//
#include <hip/hip_runtime.h>

// N=4, C=32, H=W=256, KS=3
// ws layout: p [4,32,32,32] (131072 f) | y [4,32,1024,12] (1572864 f, k-innermost pad-12)
#define N_ 4
#define C_ 32
#define H_ 256
#define W_ 256
#define PH 32
#define KSTRIDE 12
#define P_ELEMS (N_*C_*PH*PH)
#define OUT_ELEMS (N_*C_*H_*W_)

typedef float v4f __attribute__((ext_vector_type(4)));

// Kernel 1: psf -> 1/4 bilinear (avg of 2x2 at rows/cols {4o+1,4o+2}) -> maxpool2
__global__ __launch_bounds__(256) void k_downsample(
    const float* __restrict__ psf, float* __restrict__ p) {
  int tid = blockIdx.x * blockDim.x + threadIdx.x;
  if (tid >= P_ELEMS) return;
  int tx = tid & 31;
  int ty = (tid >> 5) & 31;
  int nc = tid >> 10;
  const float* x = psf + (size_t)nc * (H_ * W_);
  float m = -1e30f;
#pragma unroll
  for (int a = 0; a < 2; a++) {
#pragma unroll
    for (int b = 0; b < 2; b++) {
      int r0 = 8 * ty + 4 * a + 1;
      int c0 = 8 * tx + 4 * b + 1;
      const float* row0 = x + r0 * W_ + c0;
      const float* row1 = row0 + W_;
      float avg = 0.25f * (row0[0] + row0[1] + row1[0] + row1[1]);
      m = fmaxf(m, avg);
    }
  }
  p[tid] = m;
}

// Kernel 2: per-(n,c,quarter) block; all 9 taps per pixel, k-innermost write.
// y[((n*32+c)*1024 + hw)*12 + k] = lrelu(p.w1_{c*9+k} + b1) + (p.ws_{c*9+k} + bs)
__global__ __launch_bounds__(256) void k_conv1x1(
    const float* __restrict__ p, const float* __restrict__ w1,
    const float* __restrict__ b1, const float* __restrict__ ws,
    const float* __restrict__ bs, float* __restrict__ y) {
  int bid = blockIdx.x;             // n*128 + c*4 + q
  int q = bid & 3;
  int c = (bid >> 2) & 31;
  int n = bid >> 7;
  int hw = (q << 8) + threadIdx.x;
  const float* pn = p + ((n * C_) << 10) + hw;
  float a1[9], a2[9];
#pragma unroll
  for (int k = 0; k < 9; k++) {
    a1[k] = b1[c * 9 + k];
    a2[k] = bs[c * 9 + k];
  }
#pragma unroll
  for (int c2 = 0; c2 < C_; c2++) {
    float pv = pn[c2 << 10];
#pragma unroll
    for (int k = 0; k < 9; k++) {
      a1[k] = fmaf(pv, w1[(c * 9 + k) * C_ + c2], a1[k]);
      a2[k] = fmaf(pv, ws[(c * 9 + k) * C_ + c2], a2[k]);
    }
  }
  float r[9];
#pragma unroll
  for (int k = 0; k < 9; k++)
    r[k] = ((a1[k] >= 0.f) ? a1[k] : 0.2f * a1[k]) + a2[k];
  float* yo = y + (size_t)(((n * C_ + c) << 10) + hw) * KSTRIDE;
  v4f v0 = {r[0], r[1], r[2], r[3]};
  v4f v1 = {r[4], r[5], r[6], r[7]};
  *(v4f*)yo = v0;
  *(v4f*)(yo + 4) = v1;
  yo[8] = r[8];
}

// Kernel 3: fused x8 bilinear upsample + per-pixel 3x3 dynamic filter.
// 8 outputs/thread along w. k-innermost y: 6 corner positions x 9 taps via
// float4 loads; vertical blend hoisted to TB[3][9]; inner loop 2 fma/tap.
__global__ __launch_bounds__(256) void k_fac(
    const float* __restrict__ fm, const float* __restrict__ y,
    float* __restrict__ out) {
  int bid = blockIdx.x;
  int work = (bid >> 3) + (bid & 7) * 512;   // XCD-contiguous planes
  int g = (work << 8) + threadIdx.x;
  int m = g & 31;
  int h = (g >> 5) & 255;
  int c = (g >> 13) & 31;
  int n = g >> 18;

  float sh = fmaxf(0.125f * (float)h - 0.4375f, 0.f);
  int y0 = (int)sh;
  float wy = sh - (float)y0;
  int y1 = min(y0 + 1, 31);
  int cm1 = max(m - 1, 0);
  int cp1 = min(m + 1, 31);

  const float* yb = y + (size_t)((n * C_ + c) << 10) * KSTRIDE;
  int pos[6] = {(y0 << 5) + cm1, (y0 << 5) + m, (y0 << 5) + cp1,
                (y1 << 5) + cm1, (y1 << 5) + m, (y1 << 5) + cp1};
  float P[6][9];
#pragma unroll
  for (int i = 0; i < 6; i++) {
    const float* qp = yb + pos[i] * KSTRIDE;
    v4f A = *(const v4f*)qp;
    v4f B = *(const v4f*)(qp + 4);
    P[i][0] = A.x; P[i][1] = A.y; P[i][2] = A.z; P[i][3] = A.w;
    P[i][4] = B.x; P[i][5] = B.y; P[i][6] = B.z; P[i][7] = B.w;
    P[i][8] = qp[8];
  }
  float TB0[9], TB1[9], TB2[9];
#pragma unroll
  for (int k = 0; k < 9; k++) {
    TB0[k] = fmaf(wy, P[3][k] - P[0][k], P[0][k]);
    TB1[k] = fmaf(wy, P[4][k] - P[1][k], P[1][k]);
    TB2[k] = fmaf(wy, P[5][k] - P[2][k], P[2][k]);
  }

  const float* fb = fm + ((size_t)(n * C_ + c) << 16);
  float acc0 = 0.f, acc1 = 0.f, acc2 = 0.f, acc3 = 0.f;
  float acc4 = 0.f, acc5 = 0.f, acc6 = 0.f, acc7 = 0.f;

#pragma unroll
  for (int ky = 0; ky < 3; ky++) {
    int row = h + ky - 1;
    float fv[10];
    if (row >= 0 && row < 256) {
      const float* fr = fb + (row << 8) + (m << 3);
      v4f q0 = *(const v4f*)(fr);
      v4f q1 = *(const v4f*)(fr + 4);
      fv[0] = (m > 0) ? fr[-1] : 0.f;
      fv[1] = q0.x; fv[2] = q0.y; fv[3] = q0.z; fv[4] = q0.w;
      fv[5] = q1.x; fv[6] = q1.y; fv[7] = q1.z; fv[8] = q1.w;
      fv[9] = (m < 31) ? fr[8] : 0.f;
    } else {
#pragma unroll
      for (int t = 0; t < 10; t++) fv[t] = 0.f;
    }
#pragma unroll
    for (int kx = 0; kx < 3; kx++) {
      int k = 3 * ky + kx;
      float d0 = TB1[k] - TB0[k];
      float d1 = TB2[k] - TB1[k];
      acc0 = fmaf(fv[0 + kx], fmaf(0.5625f, d0, TB0[k]), acc0);
      acc1 = fmaf(fv[1 + kx], fmaf(0.6875f, d0, TB0[k]), acc1);
      acc2 = fmaf(fv[2 + kx], fmaf(0.8125f, d0, TB0[k]), acc2);
      acc3 = fmaf(fv[3 + kx], fmaf(0.9375f, d0, TB0[k]), acc3);
      acc4 = fmaf(fv[4 + kx], fmaf(0.0625f, d1, TB1[k]), acc4);
      acc5 = fmaf(fv[5 + kx], fmaf(0.1875f, d1, TB1[k]), acc5);
      acc6 = fmaf(fv[6 + kx], fmaf(0.3125f, d1, TB1[k]), acc6);
      acc7 = fmaf(fv[7 + kx], fmaf(0.4375f, d1, TB1[k]), acc7);
    }
  }
  float* ob = out + ((size_t)(((n * C_ + c) << 8) + h) << 8) + (m << 3);
  v4f r0 = {acc0, acc1, acc2, acc3};
  v4f r1 = {acc4, acc5, acc6, acc7};
  __builtin_nontemporal_store(r0, (v4f*)ob);
  __builtin_nontemporal_store(r1, (v4f*)(ob + 4));
}

extern "C" void kernel_launch(void* const* d_in, const int* in_sizes, int n_in,
                              void* d_out, int out_size, void* d_ws,
                              size_t ws_size, hipStream_t stream) {
  const float* psf = (const float*)d_in[0];
  const float* fm = (const float*)d_in[1];
  const float* w1 = (const float*)d_in[2];
  const float* b1 = (const float*)d_in[3];
  const float* ws = (const float*)d_in[4];
  const float* bs = (const float*)d_in[5];
  float* out = (float*)d_out;

  float* p = (float*)d_ws;
  float* y = p + P_ELEMS;

  k_downsample<<<P_ELEMS / 256, 256, 0, stream>>>(psf, p);
  k_conv1x1<<<N_ * C_ * 4, 256, 0, stream>>>(p, w1, b1, ws, bs, y);
  k_fac<<<OUT_ELEMS / (8 * 256), 256, 0, stream>>>(fm, y, out);
}